// Round 1
// baseline (107.325 us; speedup 1.0000x reference)
//
#include <hip/hip_runtime.h>

// CriticGCN: out = D^-1/2 (A+I) D^-1/2 (x W1) + b1, then @ W_head + b_head.
// Head folded through the (linear) aggregation:
//   w = W1 @ W_head (100 floats), c = b1.W_head + b_head
//   s[i] = x[i].w ; dinv[i] = rsqrt(deg[i]+1)
//   out[d] = c + dinv[d]^2 s[d] + Sum_{e:s->d} dinv[s] dinv[d] s[s]
//
// R6: deg counting moved UP to K0 (enabled by a 200KB hipMemsetAsync zero of
// deg before K0). With deg complete before K1, the score wave finalizes
// in-register: out[i] = c + dv^2*s (no seed pass, no self-term pass), and
// stashes t[i] = dv*s, dinv[i] = dv. K2 becomes the minimal edge op:
// out[dst] += t[src]*dinv[dst] -- 2 gathers + 1 atomic, zero rsqrt
// (was 3 gathers + 2 rsqrt), with 200K threads for gather-latency hiding.
//
//   M : memset deg = 0 (200 KB)
//   K0: fold w = W1@Wh, c (101 blocks) | deg[dst]++ via int4 (196 blocks)
//   K1: wave per node: s = x[i].w ; dv = rsqrt(deg+1) ;
//       out[i] = c + dv*dv*s ; t[i] = dv*s ; dinv[i] = dv
//   K2: out[dst] += t[src] * dinv[dst]   (1 edge / thread)

#define N_NODES 50000
#define F_IN    100
#define H_DIM   1024
#define N_EDGES 200000

__global__ void __launch_bounds__(256)
k0_fold_count(const float* __restrict__ W1, const float* __restrict__ b1,
              const float* __restrict__ Wh, const float* __restrict__ bh,
              const int* __restrict__ ei,
              float* __restrict__ w, float* __restrict__ c,
              unsigned* __restrict__ deg)
{
    const int b = blockIdx.x;
    const int t = threadIdx.x;
    if (b <= 100) {
        // fold: row b of W1 (or b1 for b==100) dotted with Wh (1024)
        const float* row = (b < 100) ? (W1 + (size_t)b * H_DIM) : b1;
        float s = 0.0f;
        #pragma unroll
        for (int k = 0; k < H_DIM / 256; ++k) {
            const int h = t + 256 * k;
            s += row[h] * Wh[h];
        }
        #pragma unroll
        for (int off = 32; off > 0; off >>= 1) s += __shfl_down(s, off, 64);
        __shared__ float red[4];
        const int wave = t >> 6, lane = t & 63;
        if (lane == 0) red[wave] = s;
        __syncthreads();
        if (t == 0) {
            const float tot = red[0] + red[1] + red[2] + red[3];
            if (b < 100) w[b] = tot;
            else         *c  = tot + bh[0];
        }
    } else {
        // deg count: 50000 threads x 4 edges (int4), deg pre-zeroed by memset
        const int tid = (b - 101) * 256 + t;
        if (tid < N_EDGES / 4) {
            const int4 d4 = ((const int4*)(ei + N_EDGES))[tid];
            atomicAdd(&deg[d4.x], 1u);
            atomicAdd(&deg[d4.y], 1u);
            atomicAdd(&deg[d4.z], 1u);
            atomicAdd(&deg[d4.w], 1u);
        }
    }
}

// K1 -- wave per node, pure 20 MB x-stream + in-wave finalize.
// grid = 12500 blocks * 256 = 50000 waves (exact).
__global__ void __launch_bounds__(256)
k1_score_finalize(const float* __restrict__ x, const float* __restrict__ w,
                  const float* __restrict__ c, const unsigned* __restrict__ deg,
                  float* __restrict__ tbuf, float* __restrict__ dinv,
                  float* __restrict__ out)
{
    const int tid   = blockIdx.x * 256 + threadIdx.x;
    const int gwave = tid >> 6;
    const int lane  = tid & 63;

    // hoist the (lane-0-only) deg load to overlap the reduce chain
    float dgv = 0.0f;
    if (lane == 0) dgv = (float)deg[gwave];

    const float* row = x + (size_t)gwave * F_IN;
    float s = row[lane] * w[lane];                              // 0..63
    if (lane < F_IN - 64) s += row[64 + lane] * w[64 + lane];   // 64..99
    #pragma unroll
    for (int off = 32; off > 0; off >>= 1) s += __shfl_down(s, off, 64);

    if (lane == 0) {
        const float dv = rsqrtf(dgv + 1.0f);
        tbuf[gwave] = dv * s;
        dinv[gwave] = dv;
        out[gwave]  = c[0] + dv * dv * s;   // bias + self-loop term, done
    }
}

// K2 -- minimal edge scatter: out[dst] += t[src] * dinv[dst].
// 1 edge/thread (200K threads = 3128 waves, ~12 waves/CU for latency hiding).
__global__ void __launch_bounds__(256)
k2_scatter(const int* __restrict__ ei, const float* __restrict__ tbuf,
           const float* __restrict__ dinv, float* __restrict__ out)
{
    const int tid = blockIdx.x * 256 + threadIdx.x;
    if (tid < N_EDGES) {
        const int s = ei[tid];
        const int d = ei[N_EDGES + tid];
        unsafeAtomicAdd(&out[d], tbuf[s] * dinv[d]);
    }
}

extern "C" void kernel_launch(void* const* d_in, const int* in_sizes, int n_in,
                              void* d_out, int out_size, void* d_ws, size_t ws_size,
                              hipStream_t stream)
{
    const float* x   = (const float*)d_in[0];   // (50000,100)
    const int*   ei  = (const int*)  d_in[1];   // (2,200000) int32
    const float* W1  = (const float*)d_in[2];   // (100,1024)
    const float* b1  = (const float*)d_in[3];   // (1024,)
    const float* Wh  = (const float*)d_in[4];   // (1024,)
    const float* bh  = (const float*)d_in[5];   // (1,)
    float*       out = (float*)d_out;           // (50000,)

    // ws layout (4B units): w[100] c[1] pad->128 | deg[50000] | t[50000] | dinv[50000]
    float*    ws_f = (float*)d_ws;
    float*    w    = ws_f;
    float*    c    = ws_f + 100;
    unsigned* deg  = (unsigned*)(ws_f + 128);
    float*    tbuf = ws_f + 128 + N_NODES;
    float*    dinv = ws_f + 128 + 2 * N_NODES;

    // M: zero deg (200 KB) so K0 can count immediately
    hipMemsetAsync(deg, 0, N_NODES * sizeof(unsigned), stream);
    // K0: fold w,c (101 blocks) + deg count (196 blocks)
    k0_fold_count<<<101 + (N_EDGES / 4 + 255) / 256, 256, 0, stream>>>(
        W1, b1, Wh, bh, ei, w, c, deg);
    // K1: wave-per-node score + in-wave finalize (out, t, dinv)
    k1_score_finalize<<<(N_NODES * 64) / 256, 256, 0, stream>>>(
        x, w, c, deg, tbuf, dinv, out);
    // K2: minimal normalized edge scatter
    k2_scatter<<<(N_EDGES + 255) / 256, 256, 0, stream>>>(ei, tbuf, dinv, out);
}